// Round 8
// baseline (300.744 us; speedup 1.0000x reference)
//
#include <hip/hip_runtime.h>
#include <hip/hip_bf16.h>
#include <stdint.h>

// ---------- types ----------
typedef __attribute__((ext_vector_type(8))) short short8;      // 8 bf16 (MFMA A/B frag)
typedef __attribute__((ext_vector_type(4))) float floatx4;     // 16x16 C/D frag
typedef __attribute__((ext_vector_type(16))) float floatx16;   // 32x32 C/D frag
typedef __attribute__((ext_vector_type(4))) uint16_t ushort4v;

#define MFMA16(a, b, c) __builtin_amdgcn_mfma_f32_16x16x32_bf16((a), (b), (c), 0, 0, 0)
#define MFMA32(a, b, c) __builtin_amdgcn_mfma_f32_32x32x16_bf16((a), (b), (c), 0, 0, 0)

// async global->LDS, 16B per lane; LDS dest is wave-uniform base + lane*16
#define GLOAD_LDS16(g, l)                                                          \
  __builtin_amdgcn_global_load_lds(                                                \
      (const __attribute__((address_space(1))) uint32_t*)(g),                      \
      (__attribute__((address_space(3))) uint32_t*)(l), 16, 0, 0)

// packed f32x2 -> bf16x2
#define CVTPK(lo_, hi_, out_) \
  asm("v_cvt_pk_bf16_f32 %0, %1, %2" : "=v"(out_) : "v"(lo_), "v"(hi_))
// exchange a's high 32 lanes with b's low 32 lanes
#define SWAP32(a_, b_) \
  asm("v_permlane32_swap_b32 %0, %1" : "+v"(a_), "+v"(b_))

// fp32 -> bf16 round-to-nearest-even
__device__ __forceinline__ uint16_t f2bf(float x) {
  union { float f; uint32_t u; } c; c.f = x;
  return (uint16_t)((c.u + 0x7FFFu + ((c.u >> 16) & 1u)) >> 16);
}

// ---------- fp32 -> bf16 converts, z-batched ----------
__global__ void cvt3_k(const float* __restrict__ s0, const float* __restrict__ s1,
                       const float* __restrict__ s2, uint16_t* __restrict__ dst, int n4) {
  const float* src = blockIdx.z == 0 ? s0 : (blockIdx.z == 1 ? s1 : s2);
  uint16_t* d = dst + (size_t)blockIdx.z * 8388608;  // 16MB stride
  int stride = gridDim.x * blockDim.x;
  for (int i = blockIdx.x * blockDim.x + threadIdx.x; i < n4; i += stride) {
    float4 v = ((const float4*)src)[i];
    ushort4v o;
    o.x = f2bf(v.x); o.y = f2bf(v.y); o.z = f2bf(v.z); o.w = f2bf(v.w);
    ((ushort4v*)d)[i] = o;
  }
}
__global__ void cvt4_k(const float* __restrict__ s0, const float* __restrict__ s1,
                       const float* __restrict__ s2, const float* __restrict__ s3,
                       uint16_t* __restrict__ dst, int n4) {
  const float* src = blockIdx.z == 0 ? s0 : (blockIdx.z == 1 ? s1 : (blockIdx.z == 2 ? s2 : s3));
  uint16_t* d = dst + (size_t)blockIdx.z * 1048576;  // 2MB stride
  int stride = gridDim.x * blockDim.x;
  for (int i = blockIdx.x * blockDim.x + threadIdx.x; i < n4; i += stride) {
    float4 v = ((const float4*)src)[i];
    ushort4v o;
    o.x = f2bf(v.x); o.y = f2bf(v.y); o.z = f2bf(v.z); o.w = f2bf(v.w);
    ((ushort4v*)d)[i] = o;
  }
}

// ---------- GEMM body: C[8192,1024] = (A @ W^T + bias) * scale ----------
template <int OUT_BF16>
__device__ __forceinline__ void gemm_body(const uint16_t* __restrict__ A,
                                          const uint16_t* __restrict__ W,
                                          const float* __restrict__ bias,
                                          void* __restrict__ Cout, float scale) {
  constexpr int N = 1024, K = 1024;
  __shared__ uint16_t As[128 * 32];
  __shared__ uint16_t Bs[128 * 32];
  const int t = threadIdx.x;
  const int l = t & 63;
  const int w = t >> 6;
  const int wr = w >> 1, wc = w & 1;
  const int l16 = l & 15, lhi = l >> 4;
  const int brow = blockIdx.y * 128;
  const int bcol = blockIdx.x * 128;

  floatx4 acc[4][4] = {};

  for (int k0 = 0; k0 < K; k0 += 32) {
#pragma unroll
    for (int j = 0; j < 2; ++j) {
      int c = j * 256 + t;
      int row = c >> 2;
      int ko = (c & 3) * 8;
      const uint16_t* ga = A + (size_t)(brow + row) * K + k0 + ko;
      const uint16_t* gb = W + (size_t)(bcol + row) * K + k0 + ko;
      uint16_t* la = As + (size_t)(j * 256 + w * 64) * 8;
      uint16_t* lb = Bs + (size_t)(j * 256 + w * 64) * 8;
      GLOAD_LDS16(ga, la);
      GLOAD_LDS16(gb, lb);
    }
    __syncthreads();

    short8 a[4], b[4];
#pragma unroll
    for (int m = 0; m < 4; ++m)
      a[m] = *(const short8*)&As[(wr * 64 + m * 16 + l16) * 32 + lhi * 8];
#pragma unroll
    for (int n = 0; n < 4; ++n)
      b[n] = *(const short8*)&Bs[(wc * 64 + n * 16 + l16) * 32 + lhi * 8];
#pragma unroll
    for (int m = 0; m < 4; ++m)
#pragma unroll
      for (int n = 0; n < 4; ++n)
        acc[m][n] = MFMA16(a[m], b[n], acc[m][n]);
    __syncthreads();
  }

#pragma unroll
  for (int n = 0; n < 4; ++n) {
    int col = bcol + wc * 64 + n * 16 + l16;
    float bv = bias[col];
#pragma unroll
    for (int m = 0; m < 4; ++m) {
#pragma unroll
      for (int j = 0; j < 4; ++j) {
        int row = brow + wr * 64 + m * 16 + lhi * 4 + j;
        float v = (acc[m][n][j] + bv) * scale;
        if (OUT_BF16)
          ((uint16_t*)Cout)[(size_t)row * N + col] = f2bf(v);
        else
          ((float*)Cout)[(size_t)row * N + col] = v;
      }
    }
  }
}

// fused Q/K/V projections: blockIdx.z selects the projection
__global__ __launch_bounds__(256)
void gemm_qkv_k(const uint16_t* __restrict__ XQ, const uint16_t* __restrict__ XK,
                const uint16_t* __restrict__ XV, const uint16_t* __restrict__ WQ,
                const uint16_t* __restrict__ WK, const uint16_t* __restrict__ WV,
                const float* __restrict__ bq, const float* __restrict__ bk,
                const float* __restrict__ bv, uint16_t* __restrict__ QP,
                uint16_t* __restrict__ KP, uint16_t* __restrict__ VP, float qscale) {
  const uint16_t *A, *W; const float* bi; uint16_t* C; float sc;
  if (blockIdx.z == 0)      { A = XQ; W = WQ; bi = bq; C = QP; sc = qscale; }
  else if (blockIdx.z == 1) { A = XK; W = WK; bi = bk; C = KP; sc = 1.0f; }
  else                      { A = XV; W = WV; bi = bv; C = VP; sc = 1.0f; }
  gemm_body<1>(A, W, bi, C, sc);
}

__global__ __launch_bounds__(256)
void gemm_o_k(const uint16_t* __restrict__ A, const uint16_t* __restrict__ W,
              const float* __restrict__ bias, float* __restrict__ Cout) {
  gemm_body<0>(A, W, bias, Cout, 1.0f);
}

// ---------- V transpose: VP[b,s,h*64+d] -> VT[(b*16+h)*64+d][s] ----------
__global__ __launch_bounds__(256)
void vtrans_k(const uint16_t* __restrict__ VP, uint16_t* __restrict__ VT) {
  __shared__ uint16_t T[64][66];
  const int t = threadIdx.x;
  const int bh = blockIdx.y;
  const int s0 = blockIdx.x * 64;
  const int b = bh >> 4, h = bh & 15;
  const size_t src = ((size_t)b * 2048 + s0) * 1024 + (size_t)h * 64;
#pragma unroll
  for (int it = 0; it < 2; ++it) {
    int u = it * 256 + t;
    int s = u >> 3;
    int d0 = (u & 7) * 8;
    short8 v = *(const short8*)(VP + src + (size_t)s * 1024 + d0);
#pragma unroll
    for (int i = 0; i < 8; ++i) T[s][d0 + i] = (uint16_t)v[i];
  }
  __syncthreads();
  const size_t dst = (size_t)bh * 131072 + s0;  // row stride 2048
#pragma unroll
  for (int it = 0; it < 2; ++it) {
    int u = it * 256 + t;
    int d = u >> 3;
    int ss = (u & 7) * 8;
    union { uint16_t u16[8]; short8 s8; } pk;
#pragma unroll
    for (int i = 0; i < 8; ++i) pk.u16[i] = T[ss + i][d];
    *(short8*)(VT + dst + (size_t)d * 2048 + ss) = pk.s8;
  }
}

// ---------- flash attention: 8 waves/block, shared K/V tiles, KVBLK=128 ----------
// 512 threads; waves 0..7 each own 32 q-rows (block covers 256 q). K/V LDS tiles
// shared across waves (same 64KB as R6 at double the waves/CU -> 4 waves/SIMD).
// Rowsum via in-lane f32 adds (no ones-MFMA); redistributed at epilogue.
__global__ __launch_bounds__(512, 4)
void attn_k(const uint16_t* __restrict__ Qp, const uint16_t* __restrict__ Kp,
            const uint16_t* __restrict__ Vt, uint16_t* __restrict__ AO) {
  __shared__ uint16_t Kl[2][64 * 128];   // 16KB per buffer
  __shared__ uint16_t Vl[2][64 * 128];   // 16KB per buffer

  const int t = threadIdx.x;
  const int l = t & 63, w = t >> 6;       // w = 0..7
  const int l32 = l & 31, hi = l >> 5;

  // XCD-chunked swizzle: 512 blocks, 64 per XCD -> 8 contiguous bh groups each.
  const int f = blockIdx.y * 8 + blockIdx.x;
  const int virt = (f & 7) * 64 + (f >> 3);
  const int vx = virt & 7;     // q-block (256 q each)
  const int vy = virt >> 3;    // bh

  const int q0 = vx * 256 + w * 32;
  const size_t base = (size_t)(vy >> 4) * 2048 * 1024 + (size_t)(vy & 15) * 64;
  const size_t vbg = (size_t)vy * 131072;  // (b*16+h)*64*2048

  union PAu { uint32_t u[4]; short8 s; };

  // staging: 1024 chunks per matrix per tile; 512 threads -> 2 issues each.
  // c = i*512 + t; r = c>>4, slot q = c&15, source col group q0c = q ^ (r&15).
  const uint16_t* pK[2];
  const uint16_t* pV[2];
#pragma unroll
  for (int i = 0; i < 2; ++i) {
    int c = i * 512 + t;
    int r = c >> 4, qs = c & 15;
    int q0c = qs ^ (r & 15);
    pK[i] = Kp + base + (size_t)(64 * (q0c >> 3) + r) * 1024 + (q0c & 7) * 8;
    pV[i] = Vt + vbg + (size_t)r * 2048 + q0c * 8;
  }

#define STAGE_ALL(NB)                                                 \
  {                                                                   \
    _Pragma("unroll") for (int i = 0; i < 2; ++i) {                   \
      GLOAD_LDS16(pK[i], &Kl[NB][(size_t)(i * 512 + w * 64) * 8]);    \
      GLOAD_LDS16(pV[i], &Vl[NB][(size_t)(i * 512 + w * 64) * 8]);    \
      pK[i] += 131072;  /* +128 source rows */                        \
      pV[i] += 128;     /* +128 s columns  */                         \
    }                                                                 \
  }

  // Q B-frags: lane holds Q[q0 + l32][k = ks*16 + hi*8 + i]
  short8 qf[4];
#pragma unroll
  for (int ks = 0; ks < 4; ++ks)
    qf[ks] = *(const short8*)(Qp + base + (size_t)(q0 + l32) * 1024 + ks * 16 + hi * 8);

  floatx16 of0 = {}, of1 = {};   // O[q][d] C-frags
  float rs = 0.f;                // per-lane partial rowsum for q = l32 (rows crow(r,hi))

  const int swzb = (l32 & 15);
  const int krow = l32 * 256;    // byte base of LDS row l32 (row +32 = +8192)

  STAGE_ALL(0);
  __syncthreads();

  // one 64-s half: QK -> exp(+sum) -> pack -> PV
#define HALF(CUR, H)                                                                  \
  {                                                                                   \
    floatx16 sf0 = {}, sf1 = {};                                                      \
    __builtin_amdgcn_s_setprio(1);                                                    \
    _Pragma("unroll") for (int ks = 0; ks < 4; ++ks) {                                \
      int kbyte = krow + (((H * 8 + 2 * ks + hi) ^ swzb) << 4);                       \
      short8 kf0 = *(const short8*)((char*)Kl[CUR] + kbyte);                          \
      short8 kf1 = *(const short8*)((char*)Kl[CUR] + kbyte + 8192);                   \
      sf0 = MFMA32(kf0, qf[ks], sf0);                                                 \
      sf1 = MFMA32(kf1, qf[ks], sf1);                                                 \
    }                                                                                 \
    __builtin_amdgcn_s_setprio(0);                                                    \
    _Pragma("unroll") for (int r = 0; r < 16; ++r) {                                  \
      sf0[r] = __builtin_amdgcn_exp2f(sf0[r]);                                        \
      sf1[r] = __builtin_amdgcn_exp2f(sf1[r]);                                        \
      rs += sf0[r] + sf1[r];                                                          \
    }                                                                                 \
    PAu pa[4];                                                                        \
    _Pragma("unroll") for (int sb = 0; sb < 2; ++sb) {                                \
      const floatx16& sv = sb ? sf1 : sf0;                                            \
      _Pragma("unroll") for (int ks = 0; ks < 2; ++ks) {                              \
        uint32_t a0, a1, b0, b1;                                                      \
        CVTPK(sv[8 * ks + 0], sv[8 * ks + 1], a0);                                    \
        CVTPK(sv[8 * ks + 2], sv[8 * ks + 3], a1);                                    \
        CVTPK(sv[8 * ks + 4], sv[8 * ks + 5], b0);                                    \
        CVTPK(sv[8 * ks + 6], sv[8 * ks + 7], b1);                                    \
        SWAP32(a0, b0);                                                               \
        SWAP32(a1, b1);                                                               \
        pa[sb * 2 + ks].u[0] = a0; pa[sb * 2 + ks].u[1] = a1;                         \
        pa[sb * 2 + ks].u[2] = b0; pa[sb * 2 + ks].u[3] = b1;                         \
      }                                                                               \
    }                                                                                 \
    __builtin_amdgcn_s_setprio(1);                                                    \
    _Pragma("unroll") for (int kk = 0; kk < 4; ++kk) {                                \
      int vbyte = krow + (((H * 8 + 2 * kk + hi) ^ swzb) << 4);                       \
      short8 vf0 = *(const short8*)((char*)Vl[CUR] + vbyte);                          \
      short8 vf1 = *(const short8*)((char*)Vl[CUR] + vbyte + 8192);                   \
      of0 = MFMA32(pa[kk].s, vf0, of0);                                               \
      of1 = MFMA32(pa[kk].s, vf1, of1);                                               \
    }                                                                                 \
    __builtin_amdgcn_s_setprio(0);                                                    \
  }

#define STEP128(CUR, PF)                                                              \
  {                                                                                   \
    if (PF) STAGE_ALL(CUR ^ 1);                                                       \
    HALF(CUR, 0);                                                                     \
    HALF(CUR, 1);                                                                     \
    __syncthreads();                                                                  \
  }

  for (int it = 0; it < 8; ++it) {   // 16 kv-tiles of 128, 2 per iteration
    STEP128(0, 1);
    STEP128(1, it < 7);
  }

  // --- epilogue: complete rowsums and normalize.
  // rs(lane l) covers rows crow(r,hi) of column q=l32; partner half is in lane l^32.
  rs += __shfl_xor(rs, 32);          // now rs = full rowsum for q = l32 (both hi)
#pragma unroll
  for (int r = 0; r < 16; ++r) {
    int qloc = (r & 3) + 8 * (r >> 2) + 4 * hi;       // q index of of-frag row r
    float rsq = __shfl(rs, qloc);                      // rowsum for that q
    float rinv = 1.0f / rsq;
    int qrow = q0 + qloc;
    AO[base + (size_t)qrow * 1024 + l32]      = f2bf(of0[r] * rinv);
    AO[base + (size_t)qrow * 1024 + 32 + l32] = f2bf(of1[r] * rinv);
  }
#undef STAGE_ALL
#undef HALF
#undef STEP128
}

// ---------- launch ----------
extern "C" void kernel_launch(void* const* d_in, const int* in_sizes, int n_in,
                              void* d_out, int out_size, void* d_ws, size_t ws_size,
                              hipStream_t stream) {
  const float* q  = (const float*)d_in[0];
  const float* k  = (const float*)d_in[1];
  const float* v  = (const float*)d_in[2];
  const float* Wq = (const float*)d_in[3];
  const float* bq = (const float*)d_in[4];
  const float* Wk = (const float*)d_in[5];
  const float* bk = (const float*)d_in[6];
  const float* Wv = (const float*)d_in[7];
  const float* bv = (const float*)d_in[8];
  const float* Wo = (const float*)d_in[9];
  const float* bo = (const float*)d_in[10];

  const size_t MB = 1ull << 20;
  char* ws = (char*)d_ws;
  uint16_t* XQ  = (uint16_t*)(ws + 0 * MB);    // 16MB x3, contiguous (cvt3 strides)
  uint16_t* XK  = (uint16_t*)(ws + 16 * MB);
  uint16_t* XV  = (uint16_t*)(ws + 32 * MB);
  uint16_t* WQb = (uint16_t*)(ws + 48 * MB);   // 2MB x4, contiguous (cvt4 strides)
  uint16_t* WKb = (uint16_t*)(ws + 50 * MB);
  uint16_t* WVb = (uint16_t*)(ws + 52 * MB);
  uint16_t* WOb = (uint16_t*)(ws + 54 * MB);
  uint16_t* QP  = (uint16_t*)(ws + 56 * MB);
  uint16_t* KP  = (uint16_t*)(ws + 72 * MB);
  uint16_t* VP  = (uint16_t*)(ws + 88 * MB);
  uint16_t* AO  = XQ;   // alias: XQ dead after QKV projection
  uint16_t* VT  = XK;   // alias: XK dead after QKV projection (16MB: 64 heads x 64 x 2048)

  const int NTOK = 4 * 2048;
  const int D = 1024;
  const int nBig = NTOK * D / 4;  // 2M float4
  const int nW = D * D / 4;       // 256K float4
  const float qscale = 0.125f * 1.4426950408889634f;  // softmax scale * log2e -> exp2

  cvt3_k<<<dim3(2048, 1, 3), dim3(256), 0, stream>>>(q, k, v, XQ, nBig);
  cvt4_k<<<dim3(1024, 1, 4), dim3(256), 0, stream>>>(Wq, Wk, Wv, Wo, WQb, nW);

  gemm_qkv_k<<<dim3(D / 128, NTOK / 128, 3), dim3(256), 0, stream>>>(
      XQ, XK, XV, WQb, WKb, WVb, bq, bk, bv, QP, KP, VP, qscale);

  vtrans_k<<<dim3(32, 64), dim3(256), 0, stream>>>(VP, VT);

  attn_k<<<dim3(8, 64), dim3(512), 0, stream>>>(QP, KP, VT, AO);

  gemm_o_k<<<dim3(D / 128, NTOK / 128), dim3(256), 0, stream>>>(AO, WOb, bo, (float*)d_out);
}

// Round 9
// 212.347 us; speedup vs baseline: 1.4163x; 1.4163x over previous
//
#include <hip/hip_runtime.h>
#include <hip/hip_bf16.h>
#include <stdint.h>

// ---------- types ----------
typedef __attribute__((ext_vector_type(8))) short short8;      // 8 bf16 (MFMA A/B frag)
typedef __attribute__((ext_vector_type(4))) float floatx4;     // 16x16 C/D frag
typedef __attribute__((ext_vector_type(16))) float floatx16;   // 32x32 C/D frag
typedef __attribute__((ext_vector_type(4))) uint16_t ushort4v;

#define MFMA16(a, b, c) __builtin_amdgcn_mfma_f32_16x16x32_bf16((a), (b), (c), 0, 0, 0)
#define MFMA32(a, b, c) __builtin_amdgcn_mfma_f32_32x32x16_bf16((a), (b), (c), 0, 0, 0)

// async global->LDS, 16B per lane; LDS dest is wave-uniform base + lane*16
#define GLOAD_LDS16(g, l)                                                          \
  __builtin_amdgcn_global_load_lds(                                                \
      (const __attribute__((address_space(1))) uint32_t*)(g),                      \
      (__attribute__((address_space(3))) uint32_t*)(l), 16, 0, 0)

// packed f32x2 -> bf16x2
#define CVTPK(lo_, hi_, out_) \
  asm("v_cvt_pk_bf16_f32 %0, %1, %2" : "=v"(out_) : "v"(lo_), "v"(hi_))
// exchange a's high 32 lanes with b's low 32 lanes
#define SWAP32(a_, b_) \
  asm("v_permlane32_swap_b32 %0, %1" : "+v"(a_), "+v"(b_))

// fp32 -> bf16 round-to-nearest-even
__device__ __forceinline__ uint16_t f2bf(float x) {
  union { float f; uint32_t u; } c; c.f = x;
  return (uint16_t)((c.u + 0x7FFFu + ((c.u >> 16) & 1u)) >> 16);
}

// ---------- fp32 -> bf16 converts, z-batched ----------
__global__ void cvt3_k(const float* __restrict__ s0, const float* __restrict__ s1,
                       const float* __restrict__ s2, uint16_t* __restrict__ dst, int n4) {
  const float* src = blockIdx.z == 0 ? s0 : (blockIdx.z == 1 ? s1 : s2);
  uint16_t* d = dst + (size_t)blockIdx.z * 8388608;  // 16MB stride
  int stride = gridDim.x * blockDim.x;
  for (int i = blockIdx.x * blockDim.x + threadIdx.x; i < n4; i += stride) {
    float4 v = ((const float4*)src)[i];
    ushort4v o;
    o.x = f2bf(v.x); o.y = f2bf(v.y); o.z = f2bf(v.z); o.w = f2bf(v.w);
    ((ushort4v*)d)[i] = o;
  }
}
__global__ void cvt4_k(const float* __restrict__ s0, const float* __restrict__ s1,
                       const float* __restrict__ s2, const float* __restrict__ s3,
                       uint16_t* __restrict__ dst, int n4) {
  const float* src = blockIdx.z == 0 ? s0 : (blockIdx.z == 1 ? s1 : (blockIdx.z == 2 ? s2 : s3));
  uint16_t* d = dst + (size_t)blockIdx.z * 1048576;  // 2MB stride
  int stride = gridDim.x * blockDim.x;
  for (int i = blockIdx.x * blockDim.x + threadIdx.x; i < n4; i += stride) {
    float4 v = ((const float4*)src)[i];
    ushort4v o;
    o.x = f2bf(v.x); o.y = f2bf(v.y); o.z = f2bf(v.z); o.w = f2bf(v.w);
    ((ushort4v*)d)[i] = o;
  }
}

// ---------- GEMM body: C[8192,1024] = (A @ W^T + bias) * scale ----------
template <int OUT_BF16>
__device__ __forceinline__ void gemm_body(const uint16_t* __restrict__ A,
                                          const uint16_t* __restrict__ W,
                                          const float* __restrict__ bias,
                                          void* __restrict__ Cout, float scale) {
  constexpr int N = 1024, K = 1024;
  __shared__ uint16_t As[128 * 32];
  __shared__ uint16_t Bs[128 * 32];
  const int t = threadIdx.x;
  const int l = t & 63;
  const int w = t >> 6;
  const int wr = w >> 1, wc = w & 1;
  const int l16 = l & 15, lhi = l >> 4;
  const int brow = blockIdx.y * 128;
  const int bcol = blockIdx.x * 128;

  floatx4 acc[4][4] = {};

  for (int k0 = 0; k0 < K; k0 += 32) {
#pragma unroll
    for (int j = 0; j < 2; ++j) {
      int c = j * 256 + t;
      int row = c >> 2;
      int ko = (c & 3) * 8;
      const uint16_t* ga = A + (size_t)(brow + row) * K + k0 + ko;
      const uint16_t* gb = W + (size_t)(bcol + row) * K + k0 + ko;
      uint16_t* la = As + (size_t)(j * 256 + w * 64) * 8;
      uint16_t* lb = Bs + (size_t)(j * 256 + w * 64) * 8;
      GLOAD_LDS16(ga, la);
      GLOAD_LDS16(gb, lb);
    }
    __syncthreads();

    short8 a[4], b[4];
#pragma unroll
    for (int m = 0; m < 4; ++m)
      a[m] = *(const short8*)&As[(wr * 64 + m * 16 + l16) * 32 + lhi * 8];
#pragma unroll
    for (int n = 0; n < 4; ++n)
      b[n] = *(const short8*)&Bs[(wc * 64 + n * 16 + l16) * 32 + lhi * 8];
#pragma unroll
    for (int m = 0; m < 4; ++m)
#pragma unroll
      for (int n = 0; n < 4; ++n)
        acc[m][n] = MFMA16(a[m], b[n], acc[m][n]);
    __syncthreads();
  }

#pragma unroll
  for (int n = 0; n < 4; ++n) {
    int col = bcol + wc * 64 + n * 16 + l16;
    float bv = bias[col];
#pragma unroll
    for (int m = 0; m < 4; ++m) {
#pragma unroll
      for (int j = 0; j < 4; ++j) {
        int row = brow + wr * 64 + m * 16 + lhi * 4 + j;
        float v = (acc[m][n][j] + bv) * scale;
        if (OUT_BF16)
          ((uint16_t*)Cout)[(size_t)row * N + col] = f2bf(v);
        else
          ((float*)Cout)[(size_t)row * N + col] = v;
      }
    }
  }
}

// fused Q/K/V projections: blockIdx.z selects the projection
__global__ __launch_bounds__(256)
void gemm_qkv_k(const uint16_t* __restrict__ XQ, const uint16_t* __restrict__ XK,
                const uint16_t* __restrict__ XV, const uint16_t* __restrict__ WQ,
                const uint16_t* __restrict__ WK, const uint16_t* __restrict__ WV,
                const float* __restrict__ bq, const float* __restrict__ bk,
                const float* __restrict__ bv, uint16_t* __restrict__ QP,
                uint16_t* __restrict__ KP, uint16_t* __restrict__ VP, float qscale) {
  const uint16_t *A, *W; const float* bi; uint16_t* C; float sc;
  if (blockIdx.z == 0)      { A = XQ; W = WQ; bi = bq; C = QP; sc = qscale; }
  else if (blockIdx.z == 1) { A = XK; W = WK; bi = bk; C = KP; sc = 1.0f; }
  else                      { A = XV; W = WV; bi = bv; C = VP; sc = 1.0f; }
  gemm_body<1>(A, W, bi, C, sc);
}

__global__ __launch_bounds__(256)
void gemm_o_k(const uint16_t* __restrict__ A, const uint16_t* __restrict__ W,
              const float* __restrict__ bias, float* __restrict__ Cout) {
  gemm_body<0>(A, W, bias, Cout, 1.0f);
}

// ---------- V transpose: VP[b,s,h*64+d] -> VT[(b*16+h)*64+d][s] ----------
__global__ __launch_bounds__(256)
void vtrans_k(const uint16_t* __restrict__ VP, uint16_t* __restrict__ VT) {
  __shared__ uint16_t T[64][66];
  const int t = threadIdx.x;
  const int bh = blockIdx.y;
  const int s0 = blockIdx.x * 64;
  const int b = bh >> 4, h = bh & 15;
  const size_t src = ((size_t)b * 2048 + s0) * 1024 + (size_t)h * 64;
#pragma unroll
  for (int it = 0; it < 2; ++it) {
    int u = it * 256 + t;
    int s = u >> 3;
    int d0 = (u & 7) * 8;
    short8 v = *(const short8*)(VP + src + (size_t)s * 1024 + d0);
#pragma unroll
    for (int i = 0; i < 8; ++i) T[s][d0 + i] = (uint16_t)v[i];
  }
  __syncthreads();
  const size_t dst = (size_t)bh * 131072 + s0;  // row stride 2048
#pragma unroll
  for (int it = 0; it < 2; ++it) {
    int u = it * 256 + t;
    int d = u >> 3;
    int ss = (u & 7) * 8;
    union { uint16_t u16[8]; short8 s8; } pk;
#pragma unroll
    for (int i = 0; i < 8; ++i) pk.u16[i] = T[ss + i][d];
    *(short8*)(VT + dst + (size_t)d * 2048 + ss) = pk.s8;
  }
}

// ---------- flash attention: 8 waves/block, shared K/V tiles, KVBLK=128 ----------
// 512 threads; waves 0..7 each own 32 q-rows (block covers 256 q).
// __launch_bounds__(512, 2): 2 blocks/CU -> VGPR cap 128 (R7's (512,4) forced
// 64 VGPR -> scratch spill storm; second arg is CUDA-style min-blocks/CU here).
__global__ __launch_bounds__(512, 2)
void attn_k(const uint16_t* __restrict__ Qp, const uint16_t* __restrict__ Kp,
            const uint16_t* __restrict__ Vt, uint16_t* __restrict__ AO) {
  __shared__ uint16_t Kl[2][64 * 128];   // 16KB per buffer
  __shared__ uint16_t Vl[2][64 * 128];   // 16KB per buffer

  const int t = threadIdx.x;
  const int l = t & 63, w = t >> 6;       // w = 0..7
  const int l32 = l & 31, hi = l >> 5;

  // XCD-chunked swizzle: 512 blocks, 64 per XCD -> 8 contiguous bh groups each.
  const int f = blockIdx.y * 8 + blockIdx.x;
  const int virt = (f & 7) * 64 + (f >> 3);
  const int vx = virt & 7;     // q-block (256 q each)
  const int vy = virt >> 3;    // bh

  const int q0 = vx * 256 + w * 32;
  const size_t base = (size_t)(vy >> 4) * 2048 * 1024 + (size_t)(vy & 15) * 64;
  const size_t vbg = (size_t)vy * 131072;  // (b*16+h)*64*2048

  union PAu { uint32_t u[4]; short8 s; };

  // staging: 1024 chunks per matrix per tile; 512 threads -> 2 issues each.
  // c = i*512 + t; r = c>>4, slot q = c&15, source col group q0c = q ^ (r&15).
  const uint16_t* pK[2];
  const uint16_t* pV[2];
#pragma unroll
  for (int i = 0; i < 2; ++i) {
    int c = i * 512 + t;
    int r = c >> 4, qs = c & 15;
    int q0c = qs ^ (r & 15);
    pK[i] = Kp + base + (size_t)(64 * (q0c >> 3) + r) * 1024 + (q0c & 7) * 8;
    pV[i] = Vt + vbg + (size_t)r * 2048 + q0c * 8;
  }

#define STAGE_ALL(NB)                                                 \
  {                                                                   \
    _Pragma("unroll") for (int i = 0; i < 2; ++i) {                   \
      GLOAD_LDS16(pK[i], &Kl[NB][(size_t)(i * 512 + w * 64) * 8]);    \
      GLOAD_LDS16(pV[i], &Vl[NB][(size_t)(i * 512 + w * 64) * 8]);    \
      pK[i] += 131072;  /* +128 source rows */                        \
      pV[i] += 128;     /* +128 s columns  */                         \
    }                                                                 \
  }

  // Q B-frags: lane holds Q[q0 + l32][k = ks*16 + hi*8 + i]
  short8 qf[4];
#pragma unroll
  for (int ks = 0; ks < 4; ++ks)
    qf[ks] = *(const short8*)(Qp + base + (size_t)(q0 + l32) * 1024 + ks * 16 + hi * 8);

  floatx16 of0 = {}, of1 = {};   // O[q][d] C-frags
  float rs = 0.f;                // per-lane partial rowsum for q = l32 (rows crow(r,hi))

  const int swzb = (l32 & 15);
  const int krow = l32 * 256;    // byte base of LDS row l32 (row +32 = +8192)

  STAGE_ALL(0);
  __syncthreads();

  // one 64-s half: QK -> exp(+sum) -> pack -> PV
#define HALF(CUR, H)                                                                  \
  {                                                                                   \
    floatx16 sf0 = {}, sf1 = {};                                                      \
    __builtin_amdgcn_s_setprio(1);                                                    \
    _Pragma("unroll") for (int ks = 0; ks < 4; ++ks) {                                \
      int kbyte = krow + (((H * 8 + 2 * ks + hi) ^ swzb) << 4);                       \
      short8 kf0 = *(const short8*)((char*)Kl[CUR] + kbyte);                          \
      short8 kf1 = *(const short8*)((char*)Kl[CUR] + kbyte + 8192);                   \
      sf0 = MFMA32(kf0, qf[ks], sf0);                                                 \
      sf1 = MFMA32(kf1, qf[ks], sf1);                                                 \
    }                                                                                 \
    __builtin_amdgcn_s_setprio(0);                                                    \
    _Pragma("unroll") for (int r = 0; r < 16; ++r) {                                  \
      sf0[r] = __builtin_amdgcn_exp2f(sf0[r]);                                        \
      sf1[r] = __builtin_amdgcn_exp2f(sf1[r]);                                        \
      rs += sf0[r] + sf1[r];                                                          \
    }                                                                                 \
    PAu pa[4];                                                                        \
    _Pragma("unroll") for (int sb = 0; sb < 2; ++sb) {                                \
      const floatx16& sv = sb ? sf1 : sf0;                                            \
      _Pragma("unroll") for (int ks = 0; ks < 2; ++ks) {                              \
        uint32_t a0, a1, b0, b1;                                                      \
        CVTPK(sv[8 * ks + 0], sv[8 * ks + 1], a0);                                    \
        CVTPK(sv[8 * ks + 2], sv[8 * ks + 3], a1);                                    \
        CVTPK(sv[8 * ks + 4], sv[8 * ks + 5], b0);                                    \
        CVTPK(sv[8 * ks + 6], sv[8 * ks + 7], b1);                                    \
        SWAP32(a0, b0);                                                               \
        SWAP32(a1, b1);                                                               \
        pa[sb * 2 + ks].u[0] = a0; pa[sb * 2 + ks].u[1] = a1;                         \
        pa[sb * 2 + ks].u[2] = b0; pa[sb * 2 + ks].u[3] = b1;                         \
      }                                                                               \
    }                                                                                 \
    __builtin_amdgcn_s_setprio(1);                                                    \
    _Pragma("unroll") for (int kk = 0; kk < 4; ++kk) {                                \
      int vbyte = krow + (((H * 8 + 2 * kk + hi) ^ swzb) << 4);                       \
      short8 vf0 = *(const short8*)((char*)Vl[CUR] + vbyte);                          \
      short8 vf1 = *(const short8*)((char*)Vl[CUR] + vbyte + 8192);                   \
      of0 = MFMA32(pa[kk].s, vf0, of0);                                               \
      of1 = MFMA32(pa[kk].s, vf1, of1);                                               \
    }                                                                                 \
    __builtin_amdgcn_s_setprio(0);                                                    \
  }

#define STEP128(CUR, PF)                                                              \
  {                                                                                   \
    if (PF) STAGE_ALL(CUR ^ 1);                                                       \
    HALF(CUR, 0);                                                                     \
    HALF(CUR, 1);                                                                     \
    __syncthreads();                                                                  \
  }

  for (int it = 0; it < 8; ++it) {   // 16 kv-tiles of 128, 2 per iteration
    STEP128(0, 1);
    STEP128(1, it < 7);
  }

  // --- epilogue: complete rowsums and normalize.
  // rs(lane l) covers rows crow(r,hi) of column q=l32; partner half is in lane l^32.
  rs += __shfl_xor(rs, 32);          // now rs = full rowsum for q = l32 (both hi)
#pragma unroll
  for (int r = 0; r < 16; ++r) {
    int qloc = (r & 3) + 8 * (r >> 2) + 4 * hi;       // q index of of-frag row r
    float rsq = __shfl(rs, qloc);                      // rowsum for that q
    float rinv = 1.0f / rsq;
    int qrow = q0 + qloc;
    AO[base + (size_t)qrow * 1024 + l32]      = f2bf(of0[r] * rinv);
    AO[base + (size_t)qrow * 1024 + 32 + l32] = f2bf(of1[r] * rinv);
  }
#undef STAGE_ALL
#undef HALF
#undef STEP128
}

// ---------- launch ----------
extern "C" void kernel_launch(void* const* d_in, const int* in_sizes, int n_in,
                              void* d_out, int out_size, void* d_ws, size_t ws_size,
                              hipStream_t stream) {
  const float* q  = (const float*)d_in[0];
  const float* k  = (const float*)d_in[1];
  const float* v  = (const float*)d_in[2];
  const float* Wq = (const float*)d_in[3];
  const float* bq = (const float*)d_in[4];
  const float* Wk = (const float*)d_in[5];
  const float* bk = (const float*)d_in[6];
  const float* Wv = (const float*)d_in[7];
  const float* bv = (const float*)d_in[8];
  const float* Wo = (const float*)d_in[9];
  const float* bo = (const float*)d_in[10];

  const size_t MB = 1ull << 20;
  char* ws = (char*)d_ws;
  uint16_t* XQ  = (uint16_t*)(ws + 0 * MB);    // 16MB x3, contiguous (cvt3 strides)
  uint16_t* XK  = (uint16_t*)(ws + 16 * MB);
  uint16_t* XV  = (uint16_t*)(ws + 32 * MB);
  uint16_t* WQb = (uint16_t*)(ws + 48 * MB);   // 2MB x4, contiguous (cvt4 strides)
  uint16_t* WKb = (uint16_t*)(ws + 50 * MB);
  uint16_t* WVb = (uint16_t*)(ws + 52 * MB);
  uint16_t* WOb = (uint16_t*)(ws + 54 * MB);
  uint16_t* QP  = (uint16_t*)(ws + 56 * MB);
  uint16_t* KP  = (uint16_t*)(ws + 72 * MB);
  uint16_t* VP  = (uint16_t*)(ws + 88 * MB);
  uint16_t* AO  = XQ;   // alias: XQ dead after QKV projection
  uint16_t* VT  = XK;   // alias: XK dead after QKV projection (16MB: 64 heads x 64 x 2048)

  const int NTOK = 4 * 2048;
  const int D = 1024;
  const int nBig = NTOK * D / 4;  // 2M float4
  const int nW = D * D / 4;       // 256K float4
  const float qscale = 0.125f * 1.4426950408889634f;  // softmax scale * log2e -> exp2

  cvt3_k<<<dim3(2048, 1, 3), dim3(256), 0, stream>>>(q, k, v, XQ, nBig);
  cvt4_k<<<dim3(1024, 1, 4), dim3(256), 0, stream>>>(Wq, Wk, Wv, Wo, WQb, nW);

  gemm_qkv_k<<<dim3(D / 128, NTOK / 128, 3), dim3(256), 0, stream>>>(
      XQ, XK, XV, WQb, WKb, WVb, bq, bk, bv, QP, KP, VP, qscale);

  vtrans_k<<<dim3(32, 64), dim3(256), 0, stream>>>(VP, VT);

  attn_k<<<dim3(8, 64), dim3(512), 0, stream>>>(QP, KP, VT, AO);

  gemm_o_k<<<dim3(D / 128, NTOK / 128), dim3(256), 0, stream>>>(AO, WOb, bo, (float*)d_out);
}